// Round 2
// baseline (375.435 us; speedup 1.0000x reference)
//
#include <hip/hip_runtime.h>

#define BATCH 4
#define CDIM 256
#define NDIM 4096
#define SPLITS 4
#define KSPLIT (NDIM / SPLITS)   // 1024 keys per split
#define JT 32                    // keys per j-tile
#define NTILES (KSPLIT / JT)     // 32

typedef unsigned short u16;
typedef unsigned int u32;
typedef _Float16 f16;
typedef __attribute__((ext_vector_type(8))) _Float16 half8;
typedef __attribute__((ext_vector_type(4))) float floatx4;

__device__ __forceinline__ void load_lds_128(const void* g, void* l) {
  __builtin_amdgcn_global_load_lds(
      (const __attribute__((address_space(1))) u32*)g,
      (__attribute__((address_space(3))) u32*)l, 16, 0, 0);
}

// ---------------------------------------------------------------------------
// W (f32 [C][C]) -> fp16 [C][C], rows stay contraction-contiguous.
// ---------------------------------------------------------------------------
__global__ __launch_bounds__(256) void prep_w_k(
    const float* __restrict__ wq, const float* __restrict__ wk,
    const float* __restrict__ wv, f16* __restrict__ whq,
    f16* __restrict__ whk, f16* __restrict__ whv) {
  const int gid = blockIdx.x * 256 + threadIdx.x;  // 0..24575
  const int a = gid >> 13;
  const int r = gid & 8191;
  const float* src = (a == 0) ? wq : ((a == 1) ? wk : wv);
  f16* dst = (a == 0) ? whq : ((a == 1) ? whk : whv);
  float4 v0 = *(const float4*)(src + r * 8);
  float4 v1 = *(const float4*)(src + r * 8 + 4);
  half8 h;
  h[0] = (f16)v0.x; h[1] = (f16)v0.y; h[2] = (f16)v0.z; h[3] = (f16)v0.w;
  h[4] = (f16)v1.x; h[5] = (f16)v1.y; h[6] = (f16)v1.z; h[7] = (f16)v1.w;
  *(half8*)(dst + r * 8) = h;
}

// ---------------------------------------------------------------------------
// Fused transpose + projection. grid (NDIM/128, BATCH, 3), block 256.
// ---------------------------------------------------------------------------
__global__ __launch_bounds__(256, 2) void proj_fused_k(
    const float* __restrict__ x1, const float* __restrict__ x2,
    const f16* __restrict__ whq, const float* __restrict__ bq,
    const f16* __restrict__ whk, const float* __restrict__ bk,
    const f16* __restrict__ whv, const float* __restrict__ bv,
    f16* __restrict__ qt, f16* __restrict__ kt, f16* __restrict__ vsp) {
  __shared__ __align__(16) u16 xt[256 * 132];  // 67584 B
  const int j0 = blockIdx.x * 128;
  const int b = blockIdx.y;
  const int proj = blockIdx.z;
  const float* xs = ((proj == 0) ? x1 : x2) + (size_t)b * CDIM * NDIM;
  const int t = threadIdx.x;
#pragma unroll
  for (int it = 0; it < 32; ++it) {
    const int flat = t + it * 256;       // 0..8191
    const int c = flat >> 5;
    const int n4 = (flat & 31) << 2;
    float4 v = *(const float4*)(xs + (size_t)c * NDIM + j0 + n4);
    union { f16 h[4]; uint2 u; } pk;
    pk.h[0] = (f16)v.x; pk.h[1] = (f16)v.y; pk.h[2] = (f16)v.z; pk.h[3] = (f16)v.w;
    *(uint2*)&xt[c * 132 + n4] = pk.u;
  }
  __syncthreads();
  const int wave = t >> 6, lane = t & 63, l16 = lane & 15, grp = lane >> 4;
  const f16* xth = (const f16*)xt;

  if (proj < 2) {
    const f16* w = proj ? whk : whq;
    const float* bias = proj ? bk : bq;
    f16* outp = (proj ? kt : qt) + (size_t)b * NDIM * CDIM;
    floatx4 acc[2][16];
#pragma unroll
    for (int mb = 0; mb < 2; ++mb)
#pragma unroll
      for (int nb = 0; nb < 16; ++nb) acc[mb][nb] = (floatx4){0.f, 0.f, 0.f, 0.f};
#pragma unroll
    for (int ks = 0; ks < 8; ++ks) {
      half8 a[2];
#pragma unroll
      for (int mb = 0; mb < 2; ++mb) {
        const int n = wave * 32 + mb * 16 + l16;
        half8 av;
#pragma unroll
        for (int jj = 0; jj < 8; ++jj)
          av[jj] = xth[(ks * 32 + grp * 8 + jj) * 132 + n];
        a[mb] = av;
      }
#pragma unroll
      for (int nb = 0; nb < 16; ++nb) {
        half8 bb = *(const half8*)(w + (size_t)(nb * 16 + l16) * CDIM + ks * 32 + grp * 8);
        acc[0][nb] = __builtin_amdgcn_mfma_f32_16x16x32_f16(a[0], bb, acc[0][nb], 0, 0, 0);
        acc[1][nb] = __builtin_amdgcn_mfma_f32_16x16x32_f16(a[1], bb, acc[1][nb], 0, 0, 0);
      }
    }
#pragma unroll
    for (int nb = 0; nb < 16; ++nb) {
      const int c = nb * 16 + l16;
      const float bvv = bias[c];
#pragma unroll
      for (int mb = 0; mb < 2; ++mb) {
        const int jbase = j0 + wave * 32 + mb * 16 + grp * 4;
#pragma unroll
        for (int r = 0; r < 4; ++r)
          outp[(size_t)(jbase + r) * CDIM + c] = (f16)(acc[mb][nb][r] + bvv);
      }
    }
  } else {
    f16* outp = vsp + (size_t)b * CDIM * NDIM;
    const int cw = (wave & 1) * 128;
    const int jw = (wave >> 1) * 64;
    floatx4 acc[8][4];
#pragma unroll
    for (int mb = 0; mb < 8; ++mb)
#pragma unroll
      for (int nb = 0; nb < 4; ++nb) acc[mb][nb] = (floatx4){0.f, 0.f, 0.f, 0.f};
#pragma unroll
    for (int ks = 0; ks < 8; ++ks) {
      half8 a[8];
#pragma unroll
      for (int mb = 0; mb < 8; ++mb)
        a[mb] = *(const half8*)(whv + (size_t)(cw + mb * 16 + l16) * CDIM + ks * 32 + grp * 8);
#pragma unroll
      for (int nb = 0; nb < 4; ++nb) {
        const int n = jw + nb * 16 + l16;
        half8 bv8;
#pragma unroll
        for (int jj = 0; jj < 8; ++jj)
          bv8[jj] = xth[(ks * 32 + grp * 8 + jj) * 132 + n];
#pragma unroll
        for (int mb = 0; mb < 8; ++mb)
          acc[mb][nb] = __builtin_amdgcn_mfma_f32_16x16x32_f16(a[mb], bv8, acc[mb][nb], 0, 0, 0);
      }
    }
#pragma unroll
    for (int mb = 0; mb < 8; ++mb)
#pragma unroll
      for (int r = 0; r < 4; ++r) {
        const int c = cw + mb * 16 + grp * 4 + r;
        const float bvv = bv[c];
#pragma unroll
        for (int nb = 0; nb < 4; ++nb) {
          const int j = j0 + jw + nb * 16 + l16;
          outp[(size_t)c * NDIM + j] = (f16)(acc[mb][nb][r] + bvv);
        }
      }
  }
}

// ---------------------------------------------------------------------------
// Flash attention partial — swapped-QK^T in-register softmax version:
//  - S' = mfma(K,Q): query = lane l16, keys in regs -> stats fully in-register
//    (no LDS P roundtrip, no P scratch, scores stay f32)
//  - P B-frag rebuilt via 8 shfl + selects per tile
//  - defer-max (THR=8): rescale only when tile max exceeds running max by >8
//  - per-mb schedule {sm0 -> PV0 -> sm1 -> PV1}: PV(mb0) independent of
//    softmax(mb1) so MFMA overlaps the shfl/exp chain (V re-read per mb)
//  - K/V double-buffered, ONE barrier per tile, prefetch-after-barrier
// Grid 512 = 32 q-tiles x (4 b x 4 split); 4 waves, 32 q/wave, 2 blocks/CU.
// LDS: dbuf 2x32 KB = 64 KB.
// ---------------------------------------------------------------------------
__global__ __launch_bounds__(256, 2) void flash_k(
    const f16* __restrict__ qt, const f16* __restrict__ kt,
    const f16* __restrict__ vs, f16* __restrict__ pO,
    float* __restrict__ pm, float* __restrict__ pl) {
  __shared__ __align__(16) u16 smem[32768];  // 64 KB K/V dbuf
  const int bx = blockIdx.x;
  const int c16 = bx & 15;                   // XCD-pinned (b,s)
  const int b = c16 >> 2, s = c16 & 3;
  const int i0 = (bx >> 4) * 128;
  const int jwin = s * KSPLIT;
  const f16* Q = qt + (size_t)b * NDIM * CDIM;
  const f16* K = kt + (size_t)b * NDIM * CDIM;
  const f16* V = vs + (size_t)b * CDIM * NDIM;
  const int tid = threadIdx.x;
  const int wave = tid >> 6, lane = tid & 63, l16 = lane & 15, grp = lane >> 4;
  // shfl sources for the P exchange: grps (grp&1)*2 and (grp&1)*2+1
  const int shA = ((grp & 1) << 5) + l16;
  const int shB = shA + 16;
  const bool hi = (grp & 2) != 0;

  // persistent Q frags: 2 m-blocks of 16 q
  half8 qf[2][8];
#pragma unroll
  for (int mb = 0; mb < 2; ++mb)
#pragma unroll
    for (int ks = 0; ks < 8; ++ks)
      qf[mb][ks] = *(const half8*)(Q + (size_t)(i0 + wave * 32 + mb * 16 + l16) * CDIM +
                                   ks * 32 + grp * 8);

  floatx4 O[2][16];  // O^T: row=channel-local grp*4+r, col=query l16
#pragma unroll
  for (int mb = 0; mb < 2; ++mb)
#pragma unroll
    for (int cb = 0; cb < 16; ++cb) O[mb][cb] = (floatx4){0.f, 0.f, 0.f, 0.f};
  float m_[2] = {-1e30f, -1e30f};
  float lsum[2] = {0.f, 0.f};

  const int kr2 = lane >> 5, kp = lane & 31;   // K staging: 2 rows/instr
  const int vrow = lane >> 2, vp = lane & 3;   // V staging: 16 rows/instr

#define STAGE(J0, BUF)                                                         \
  {                                                                            \
    u16* sK = smem + (BUF) * 16384;                                            \
    u16* sV = sK + 8192;                                                       \
    _Pragma("unroll") for (int it = 0; it < 4; ++it) {                         \
      const int row = wave * 8 + it * 2 + kr2;                                 \
      const int g = kp ^ (row & 7);                                            \
      load_lds_128(K + (size_t)((J0) + row) * CDIM + g * 8,                    \
                   &sK[(wave * 8 + it * 2) * 256]);                            \
    }                                                                          \
    _Pragma("unroll") for (int it = 0; it < 4; ++it) {                         \
      const int c = wave * 64 + it * 16 + vrow;                                \
      const int g = vp ^ ((c >> 2) & 3);                                       \
      load_lds_128(V + (size_t)c * NDIM + (J0) + g * 8,                        \
                   &sV[(wave * 64 + it * 16) * 32]);                           \
    }                                                                          \
  }

  STAGE(jwin, 0)

  for (int tt = 0; tt < NTILES; ++tt) {
    __syncthreads();  // drains prefetch(tt); frees buffer (tt+1)&1
    if (tt + 1 < NTILES) STAGE(jwin + (tt + 1) * JT, (tt + 1) & 1)
    u16* bK = smem + (tt & 1) * 16384;
    u16* bV = bK + 8192;

    // ---- S' = K Q^T (swapped: row=key grp*4+r (+16*jb), col=query l16) ----
    floatx4 S[2][2];
#pragma unroll
    for (int mb = 0; mb < 2; ++mb)
#pragma unroll
      for (int jb = 0; jb < 2; ++jb) S[mb][jb] = (floatx4){0.f, 0.f, 0.f, 0.f};
#pragma unroll
    for (int ks = 0; ks < 8; ++ks) {
      const int chunk = ks * 4 + grp;
#pragma unroll
      for (int jb = 0; jb < 2; ++jb) {
        const int row = jb * 16 + l16;
        half8 kf = *(const half8*)&bK[row * 256 + ((chunk ^ (row & 7)) << 3)];
        S[0][jb] = __builtin_amdgcn_mfma_f32_16x16x32_f16(kf, qf[0][ks], S[0][jb], 0, 0, 0);
        S[1][jb] = __builtin_amdgcn_mfma_f32_16x16x32_f16(kf, qf[1][ks], S[1][jb], 0, 0, 0);
      }
    }

    // ---- per-mb: in-register softmax -> P exchange -> PV ----
#pragma unroll
    for (int mb = 0; mb < 2; ++mb) {
      // lane holds 8 scores of query l16: keys jb*16 + grp*4 + r
      float u[8];
#pragma unroll
      for (int jb = 0; jb < 2; ++jb)
#pragma unroll
        for (int r = 0; r < 4; ++r) u[jb * 4 + r] = S[mb][jb][r];
      float mx = fmaxf(fmaxf(fmaxf(u[0], u[1]), fmaxf(u[2], u[3])),
                       fmaxf(fmaxf(u[4], u[5]), fmaxf(u[6], u[7])));
      mx = fmaxf(mx, __shfl_xor(mx, 16, 64));
      mx = fmaxf(mx, __shfl_xor(mx, 32, 64));
      // defer-max: rescale only when headroom exceeded (P <= e^8, f16-safe)
      if (!__all(mx - m_[mb] <= 8.0f)) {
        const float mnew = fmaxf(m_[mb], mx);
        const float al = __expf(m_[mb] - mnew);
        m_[mb] = mnew;
        lsum[mb] *= al;
#pragma unroll
        for (int cb = 0; cb < 16; ++cb) O[mb][cb] *= al;
      }
      const float mm = m_[mb];
      float pe[8];
#pragma unroll
      for (int j = 0; j < 8; ++j) pe[j] = __expf(u[j] - mm);
      lsum[mb] += ((pe[0] + pe[1]) + (pe[2] + pe[3])) +
                  ((pe[4] + pe[5]) + (pe[6] + pe[7]));
      // pack to f16 pairs: w[0]=(k 4g,4g+1) w[1]=(4g+2,4g+3) w[2],w[3]=+16
      union HW { half8 h; u32 w[4]; };
      HW pk;
#pragma unroll
      for (int j = 0; j < 8; ++j) pk.h[j] = (f16)pe[j];
      // exchange to B-frag layout: lane needs keys grp*8..grp*8+7
      const u32 a0 = __shfl(pk.w[0], shA), a1 = __shfl(pk.w[1], shA);
      const u32 a2 = __shfl(pk.w[2], shA), a3 = __shfl(pk.w[3], shA);
      const u32 b0 = __shfl(pk.w[0], shB), b1 = __shfl(pk.w[1], shB);
      const u32 b2 = __shfl(pk.w[2], shB), b3 = __shfl(pk.w[3], shB);
      HW pa;
      pa.w[0] = hi ? a2 : a0;
      pa.w[1] = hi ? a3 : a1;
      pa.w[2] = hi ? b2 : b0;
      pa.w[3] = hi ? b3 : b1;

      // ---- O^T[mb] += V * P^T ----
#pragma unroll
      for (int cb = 0; cb < 16; ++cb) {
        const int c = cb * 16 + l16;
        half8 vf = *(const half8*)&bV[c * 32 + ((grp ^ ((c >> 2) & 3)) << 3)];
        O[mb][cb] = __builtin_amdgcn_mfma_f32_16x16x32_f16(vf, pa.h, O[mb][cb], 0, 0, 0);
      }
    }
  }

  // ---- final l reduce across the 4 grp lane-groups ----
#pragma unroll
  for (int mb = 0; mb < 2; ++mb) {
    lsum[mb] += __shfl_xor(lsum[mb], 16, 64);
    lsum[mb] += __shfl_xor(lsum[mb], 32, 64);
  }
  if (grp == 0) {
    const int base = (b * SPLITS + s) * NDIM + i0;
#pragma unroll
    for (int mb = 0; mb < 2; ++mb) {
      const int i = wave * 32 + mb * 16 + l16;
      pm[base + i] = m_[mb];
      pl[base + i] = lsum[mb];
    }
  }

  // ---- epilogue: direct stores from O^T C-layout ----
  const size_t pbase = (size_t)(b * SPLITS + s) * CDIM * NDIM;
#pragma unroll
  for (int mb = 0; mb < 2; ++mb) {
    const int i = i0 + wave * 32 + mb * 16 + l16;
#pragma unroll
    for (int cb = 0; cb < 16; ++cb) {
      const int c = cb * 16 + grp * 4;
#pragma unroll
      for (int r = 0; r < 4; ++r)
        pO[pbase + (size_t)(c + r) * NDIM + i] = (f16)O[mb][cb][r];
    }
  }
}

// ---------------------------------------------------------------------------
// Combine 4 split partials: out[b][c][i] = sum_s u_s(i) * O_s[c][i]
// ---------------------------------------------------------------------------
__global__ __launch_bounds__(256) void combine_k(
    const f16* __restrict__ pO, const float* __restrict__ pm,
    const float* __restrict__ pl, float* __restrict__ out) {
  __shared__ float su[SPLITS][64];
  const int b = blockIdx.x >> 6;
  const int i0 = (blockIdx.x & 63) * 64;
  const int t = threadIdx.x;
  if (t < 64) {
    const int i = i0 + t;
    float mv[SPLITS], w[SPLITS];
    float M = -3e38f;
#pragma unroll
    for (int s = 0; s < SPLITS; ++s) {
      mv[s] = pm[(b * SPLITS + s) * NDIM + i];
      M = fmaxf(M, mv[s]);
    }
    float L = 0.f;
#pragma unroll
    for (int s = 0; s < SPLITS; ++s) {
      w[s] = __expf(mv[s] - M);
      L += pl[(b * SPLITS + s) * NDIM + i] * w[s];
    }
    const float invL = 1.0f / L;
#pragma unroll
    for (int s = 0; s < SPLITS; ++s) su[s][t] = w[s] * invL;
  }
  __syncthreads();
#pragma unroll
  for (int it = 0; it < 8; ++it) {
    const int task = t + it * 256;
    const int c = task >> 3, p = (task & 7) * 8;
    float acc[8] = {0.f, 0.f, 0.f, 0.f, 0.f, 0.f, 0.f, 0.f};
#pragma unroll
    for (int s = 0; s < SPLITS; ++s) {
      const f16* src = pO + ((size_t)(b * SPLITS + s) * CDIM + c) * NDIM + i0 + p;
      half8 h = *(const half8*)src;
#pragma unroll
      for (int j = 0; j < 8; ++j) acc[j] += su[s][p + j] * (float)h[j];
    }
    float* dst = out + ((size_t)b * CDIM + c) * NDIM + i0 + p;
    float4 lo = {acc[0], acc[1], acc[2], acc[3]};
    float4 hi = {acc[4], acc[5], acc[6], acc[7]};
    *(float4*)dst = lo;
    *(float4*)(dst + 4) = hi;
  }
}

// ---------------------------------------------------------------------------
extern "C" void kernel_launch(void* const* d_in, const int* in_sizes, int n_in,
                              void* d_out, int out_size, void* d_ws, size_t ws_size,
                              hipStream_t stream) {
  const float* x1 = (const float*)d_in[0];
  const float* x2 = (const float*)d_in[1];
  const float* Wq = (const float*)d_in[2];
  const float* bq = (const float*)d_in[3];
  const float* Wk = (const float*)d_in[4];
  const float* bk = (const float*)d_in[5];
  const float* Wv = (const float*)d_in[6];
  const float* bv = (const float*)d_in[7];
  float* out = (float*)d_out;
  char* ws = (char*)d_ws;
  f16* qtp = (f16*)(ws + 0);
  f16* ktp = (f16*)(ws + 8388608);
  f16* vsp = (f16*)(ws + 16777216);
  f16* whq = (f16*)(ws + 41943040);
  f16* whk = whq + CDIM * CDIM;
  f16* whv = whk + CDIM * CDIM;
  f16* pO = (f16*)(ws + 25165824);   // 32 MB region (dead xt space)
  float* pm = (float*)(ws + 58720256);
  float* pl = (float*)(ws + 58982400);

  prep_w_k<<<dim3(96), dim3(256), 0, stream>>>(Wq, Wk, Wv, whq, whk, whv);
  proj_fused_k<<<dim3(NDIM / 128, BATCH, 3), dim3(256), 0, stream>>>(
      x1, x2, whq, bq, whk, bk, whv, bv, qtp, ktp, vsp);
  flash_k<<<dim3(512), dim3(256), 0, stream>>>(qtp, ktp, vsp, pO, pm, pl);
  combine_k<<<dim3(256), dim3(256), 0, stream>>>(pO, pm, pl, out);
}